// Round 4
// baseline (1247.819 us; speedup 1.0000x reference)
//
#include <hip/hip_runtime.h>
#include <math.h>

#define NB 32
#define NQ 256
#define NK 256
#define NH 128
#define C2 2.8853900817779268f   // 2*log2(e)

__global__ __launch_bounds__(512, 8) void addattn_kernel(
    const float* __restrict__ q_g, const float* __restrict__ k_g,
    const float* __restrict__ v_g, const float* __restrict__ w_g,
    float* __restrict__ out)
{
    __shared__ float kbuf[8192];    // 32 KB: 2 x 16KB double-buffered 32-row tiles (Ek, then V)
    __shared__ float strip[2048];   // 8 KB: per-wave 256 f32 (Eq; later ping-pong attn slices)

    const int tid  = threadIdx.x;
    const int lane = tid & 63;
    const int wv   = tid >> 6;      // 0..7
    const int kk   = lane & 31;
    const int qh   = lane >> 5;     // which of the wave's 2 q rows

    // XCD-grouped remap (512 blocks, 64 per XCD share batches -> L2 locality)
    const int o  = ((blockIdx.x & 7) << 6) + (blockIdx.x >> 3);
    const int b  = o >> 4;
    const int q0 = (o & 15) << 4;   // 16 q rows per block

    // ---- Eq = exp2(C2*q) into wave-private strip ----
    {
        const float* qp = q_g + ((size_t)(b * NQ + q0 + (wv << 1) + qh)) * NH + (kk << 2);
        float4 qv = *(const float4*)qp;
        float4 E;
        E.x = __builtin_amdgcn_exp2f(C2 * qv.x);
        E.y = __builtin_amdgcn_exp2f(C2 * qv.y);
        E.z = __builtin_amdgcn_exp2f(C2 * qv.z);
        E.w = __builtin_amdgcn_exp2f(C2 * qv.w);
        *(float4*)&strip[(wv << 8) + (qh << 7) + (kk << 2)] = E;
    }

    const float4* kg4 = (const float4*)(k_g + (size_t)b * NK * NH);
    const float4* vg4 = (const float4*)(v_g + (size_t)b * NK * NH);
    const int kr = tid >> 5, hc = tid & 31;   // staging coords (1024 float4 per 32-row tile)

    // ---- K tile 0 prologue ----
    {
        float4 p0 = kg4[tid];
        float4 p1 = kg4[tid + 512];
        float4 E0, E1;
        E0.x = __builtin_amdgcn_exp2f(C2 * p0.x); E0.y = __builtin_amdgcn_exp2f(C2 * p0.y);
        E0.z = __builtin_amdgcn_exp2f(C2 * p0.z); E0.w = __builtin_amdgcn_exp2f(C2 * p0.w);
        E1.x = __builtin_amdgcn_exp2f(C2 * p1.x); E1.y = __builtin_amdgcn_exp2f(C2 * p1.y);
        E1.z = __builtin_amdgcn_exp2f(C2 * p1.z); E1.w = __builtin_amdgcn_exp2f(C2 * p1.w);
        *(float4*)&kbuf[(hc << 7) + (((kr + hc) & 31) << 2)]      = E0;
        *(float4*)&kbuf[(hc << 7) + (((kr + 16 + hc) & 31) << 2)] = E1;
    }
    __syncthreads();

    // ---- score phase: 8 tiles of 32 k-rows, double-buffered; t==7 issues V tile 0 ----
    float sc[8];
    float4 vst0, vst1;
    const float* eqp = strip + (wv << 8) + (qh << 7);
    #pragma unroll 1
    for (int t = 0; t < 8; ++t) {
        float4 p0, p1;
        if (t < 7) { p0 = kg4[(t + 1) * 1024 + tid]; p1 = kg4[(t + 1) * 1024 + tid + 512]; }
        else       { vst0 = vg4[tid];                vst1 = vg4[tid + 512]; }
        const float* kb = kbuf + ((t & 1) << 12);
        float s = 0.f;
        #pragma unroll
        for (int h4 = 0; h4 < 32; ++h4) {
            float4 w4 = *(const float4*)(w_g + (h4 << 2));                     // uniform, L1
            float4 e4 = *(const float4*)(eqp + (h4 << 2));                     // 2-addr bcast
            float4 k4 = *(const float4*)(kb + (h4 << 7) + (((kk + h4) & 31) << 2));
            #pragma unroll
            for (int i = 0; i < 4; ++i) {
                float tden = fmaf((&e4.x)[i], (&k4.x)[i], 1.0f);
                s = fmaf((&w4.x)[i], __builtin_amdgcn_rcpf(tden), s);
            }
        }
        sc[t] = s;    // score for k = t*32 + kk (times -2, folded below)
        if (t < 7) {
            float4 E0, E1;
            E0.x = __builtin_amdgcn_exp2f(C2 * p0.x); E0.y = __builtin_amdgcn_exp2f(C2 * p0.y);
            E0.z = __builtin_amdgcn_exp2f(C2 * p0.z); E0.w = __builtin_amdgcn_exp2f(C2 * p0.w);
            E1.x = __builtin_amdgcn_exp2f(C2 * p1.x); E1.y = __builtin_amdgcn_exp2f(C2 * p1.y);
            E1.z = __builtin_amdgcn_exp2f(C2 * p1.z); E1.w = __builtin_amdgcn_exp2f(C2 * p1.w);
            float* kbn = kbuf + (((t + 1) & 1) << 12);
            *(float4*)&kbn[(hc << 7) + (((kr + hc) & 31) << 2)]      = E0;
            *(float4*)&kbn[(hc << 7) + (((kr + 16 + hc) & 31) << 2)] = E1;
        }
        __syncthreads();
    }

    // ---- softmax (wave-local, per half-wave = one q row); V tile 0 latency overlaps ----
    // score = -2*acc; fold *LOG2E: x = -C2*acc  (exp(score-m) = exp2(x - xm))
    #pragma unroll
    for (int j = 0; j < 8; ++j) sc[j] *= -C2;
    float m = sc[0];
    #pragma unroll
    for (int j = 1; j < 8; ++j) m = fmaxf(m, sc[j]);
    #pragma unroll
    for (int off = 16; off; off >>= 1) m = fmaxf(m, __shfl_xor(m, off));
    float ssum = 0.f;
    #pragma unroll
    for (int j = 0; j < 8; ++j) { sc[j] = __builtin_amdgcn_exp2f(sc[j] - m); ssum += sc[j]; }
    #pragma unroll
    for (int off = 16; off; off >>= 1) ssum += __shfl_xor(ssum, off);
    const float inv = __builtin_amdgcn_rcpf(ssum);

    // stage V tile 0 (linear [32][128]) + attn slice 0 (ping-pong slot 0)
    ((float4*)kbuf)[tid]       = vst0;
    ((float4*)kbuf)[tid + 512] = vst1;
    strip[(wv << 8) + (qh << 5) + kk] = sc[0] * inv;
    __syncthreads();

    // ---- PV phase: 8 tiles of 32 V-rows, double-buffered ----
    float o0 = 0.f, o1 = 0.f, o2 = 0.f, o3 = 0.f;
    #pragma unroll 1
    for (int t = 0; t < 8; ++t) {
        float4 v0, v1;
        if (t < 7) { v0 = vg4[(t + 1) * 1024 + tid]; v1 = vg4[(t + 1) * 1024 + tid + 512]; }
        const float* vb = kbuf + ((t & 1) << 12);
        const float* ap = strip + (wv << 8) + ((t & 1) << 7) + (qh << 5);
        #pragma unroll
        for (int g = 0; g < 8; ++g) {
            float4 at = *(const float4*)(ap + (g << 2));      // uniform bcast
            #pragma unroll
            for (int i = 0; i < 4; ++i) {
                int r = (g << 2) + i;
                float a = (&at.x)[i];
                float4 vv = *(const float4*)(vb + (r << 7) + (kk << 2));
                o0 = fmaf(a, vv.x, o0);
                o1 = fmaf(a, vv.y, o1);
                o2 = fmaf(a, vv.z, o2);
                o3 = fmaf(a, vv.w, o3);
            }
        }
        if (t < 7) {
            strip[(wv << 8) + (((t + 1) & 1) << 7) + (qh << 5) + kk] = sc[t + 1] * inv;
            float* vbn = kbuf + (((t + 1) & 1) << 12);
            ((float4*)vbn)[tid]       = v0;
            ((float4*)vbn)[tid + 512] = v1;
        }
        __syncthreads();
    }

    float4 oo; oo.x = o0; oo.y = o1; oo.z = o2; oo.w = o3;
    float* orow = out + ((size_t)(b * NQ) + q0 + (wv << 1) + qh) * NH;
    *(float4*)&orow[kk << 2] = oo;
}

extern "C" void kernel_launch(void* const* d_in, const int* in_sizes, int n_in,
                              void* d_out, int out_size, void* d_ws, size_t ws_size,
                              hipStream_t stream) {
    const float* q = (const float*)d_in[0];
    const float* k = (const float*)d_in[1];
    const float* v = (const float*)d_in[2];
    const float* w = (const float*)d_in[3];
    float* out = (float*)d_out;
    addattn_kernel<<<512, 512, 0, stream>>>(q, k, v, w, out);
}

// Round 5
// 447.889 us; speedup vs baseline: 2.7860x; 2.7860x over previous
//
#include <hip/hip_runtime.h>
#include <math.h>

#define NB 32
#define NQ 256
#define NK 256
#define NH 128
#define C2 2.8853900817779268f   // 2*log2(e)

__global__ __launch_bounds__(512, 6) void addattn_kernel(
    const float* __restrict__ q_g, const float* __restrict__ k_g,
    const float* __restrict__ v_g, const float* __restrict__ w_g,
    float* __restrict__ out)
{
    __shared__ float kbuf[8192];    // 32 KB: 2 x 16KB double-buffered 32-row tiles (Ek, then V)
    __shared__ float strip[2048];   // 8 KB: per-wave 256 f32 (Eq; later ping-pong attn slices)

    const int tid  = threadIdx.x;
    const int lane = tid & 63;
    const int wv   = tid >> 6;      // 0..7
    const int kk   = lane & 31;
    const int qh   = lane >> 5;     // which of the wave's 2 q rows

    // XCD-grouped remap (512 blocks, 64 per XCD share batches -> L2 locality)
    const int o  = ((blockIdx.x & 7) << 6) + (blockIdx.x >> 3);
    const int b  = o >> 4;
    const int q0 = (o & 15) << 4;   // 16 q rows per block

    // ---- Eq = exp2(C2*q) into wave-private strip ----
    {
        const float* qp = q_g + ((size_t)(b * NQ + q0 + (wv << 1) + qh)) * NH + (kk << 2);
        float4 qv = *(const float4*)qp;
        float4 E;
        E.x = __builtin_amdgcn_exp2f(C2 * qv.x);
        E.y = __builtin_amdgcn_exp2f(C2 * qv.y);
        E.z = __builtin_amdgcn_exp2f(C2 * qv.z);
        E.w = __builtin_amdgcn_exp2f(C2 * qv.w);
        *(float4*)&strip[(wv << 8) + (qh << 7) + (kk << 2)] = E;
    }

    const float4* kg4 = (const float4*)(k_g + (size_t)b * NK * NH);
    const float4* vg4 = (const float4*)(v_g + (size_t)b * NK * NH);
    const int kr = tid >> 5, hc = tid & 31;   // staging coords (1024 float4 per 32-row tile)

    // ---- K tile 0 prologue ----
    {
        float4 p0 = kg4[tid];
        float4 p1 = kg4[tid + 512];
        float4 E0, E1;
        E0.x = __builtin_amdgcn_exp2f(C2 * p0.x); E0.y = __builtin_amdgcn_exp2f(C2 * p0.y);
        E0.z = __builtin_amdgcn_exp2f(C2 * p0.z); E0.w = __builtin_amdgcn_exp2f(C2 * p0.w);
        E1.x = __builtin_amdgcn_exp2f(C2 * p1.x); E1.y = __builtin_amdgcn_exp2f(C2 * p1.y);
        E1.z = __builtin_amdgcn_exp2f(C2 * p1.z); E1.w = __builtin_amdgcn_exp2f(C2 * p1.w);
        *(float4*)&kbuf[(hc << 7) + (((kr + hc) & 31) << 2)]      = E0;
        *(float4*)&kbuf[(hc << 7) + (((kr + 16 + hc) & 31) << 2)] = E1;
    }
    __syncthreads();

    // ---- score phase: 8 tiles of 32 k-rows, double-buffered; t==7 issues V tile 0 ----
    // FULLY UNROLLED so sc[] stays in registers (rule #20: no runtime-indexed reg arrays)
    float sc[8];
    float4 vst0, vst1;
    const float* eqp = strip + (wv << 8) + (qh << 7);
    #pragma unroll
    for (int t = 0; t < 8; ++t) {
        float4 p0, p1;
        if (t < 7) { p0 = kg4[(t + 1) * 1024 + tid]; p1 = kg4[(t + 1) * 1024 + tid + 512]; }
        else       { vst0 = vg4[tid];                vst1 = vg4[tid + 512]; }
        const float* kb = kbuf + ((t & 1) << 12);
        float s = 0.f;
        #pragma unroll
        for (int h4 = 0; h4 < 32; ++h4) {
            float4 w4 = *(const float4*)(w_g + (h4 << 2));                     // uniform, L1
            float4 e4 = *(const float4*)(eqp + (h4 << 2));                     // 2-addr bcast
            float4 k4 = *(const float4*)(kb + (h4 << 7) + (((kk + h4) & 31) << 2));
            #pragma unroll
            for (int i = 0; i < 4; ++i) {
                float tden = fmaf((&e4.x)[i], (&k4.x)[i], 1.0f);
                s = fmaf((&w4.x)[i], __builtin_amdgcn_rcpf(tden), s);
            }
        }
        sc[t] = s;    // score for k = t*32 + kk (times -2, folded below)
        if (t < 7) {
            float4 E0, E1;
            E0.x = __builtin_amdgcn_exp2f(C2 * p0.x); E0.y = __builtin_amdgcn_exp2f(C2 * p0.y);
            E0.z = __builtin_amdgcn_exp2f(C2 * p0.z); E0.w = __builtin_amdgcn_exp2f(C2 * p0.w);
            E1.x = __builtin_amdgcn_exp2f(C2 * p1.x); E1.y = __builtin_amdgcn_exp2f(C2 * p1.y);
            E1.z = __builtin_amdgcn_exp2f(C2 * p1.z); E1.w = __builtin_amdgcn_exp2f(C2 * p1.w);
            float* kbn = kbuf + (((t + 1) & 1) << 12);
            *(float4*)&kbn[(hc << 7) + (((kr + hc) & 31) << 2)]      = E0;
            *(float4*)&kbn[(hc << 7) + (((kr + 16 + hc) & 31) << 2)] = E1;
        }
        __syncthreads();
    }

    // ---- softmax (per half-wave = one q row); V tile 0 load latency overlaps ----
    #pragma unroll
    for (int j = 0; j < 8; ++j) sc[j] *= -C2;     // -2*acc, *log2e folded
    float m = sc[0];
    #pragma unroll
    for (int j = 1; j < 8; ++j) m = fmaxf(m, sc[j]);
    #pragma unroll
    for (int off = 16; off; off >>= 1) m = fmaxf(m, __shfl_xor(m, off));
    float ssum = 0.f;
    #pragma unroll
    for (int j = 0; j < 8; ++j) { sc[j] = __builtin_amdgcn_exp2f(sc[j] - m); ssum += sc[j]; }
    #pragma unroll
    for (int off = 16; off; off >>= 1) ssum += __shfl_xor(ssum, off);
    const float inv = __builtin_amdgcn_rcpf(ssum);

    // stage V tile 0 (linear [32][128]) + attn slice 0 (ping-pong slot 0)
    ((float4*)kbuf)[tid]       = vst0;
    ((float4*)kbuf)[tid + 512] = vst1;
    strip[(wv << 8) + (qh << 5) + kk] = sc[0] * inv;
    __syncthreads();

    // ---- PV phase: 8 tiles of 32 V-rows, double-buffered (fully unrolled) ----
    float o0 = 0.f, o1 = 0.f, o2 = 0.f, o3 = 0.f;
    #pragma unroll
    for (int t = 0; t < 8; ++t) {
        float4 v0, v1;
        if (t < 7) { v0 = vg4[(t + 1) * 1024 + tid]; v1 = vg4[(t + 1) * 1024 + tid + 512]; }
        const float* vb = kbuf + ((t & 1) << 12);
        const float* ap = strip + (wv << 8) + ((t & 1) << 7) + (qh << 5);
        #pragma unroll
        for (int g = 0; g < 8; ++g) {
            float4 at = *(const float4*)(ap + (g << 2));      // uniform bcast
            #pragma unroll
            for (int i = 0; i < 4; ++i) {
                int r = (g << 2) + i;
                float a = (&at.x)[i];
                float4 vv = *(const float4*)(vb + (r << 7) + (kk << 2));
                o0 = fmaf(a, vv.x, o0);
                o1 = fmaf(a, vv.y, o1);
                o2 = fmaf(a, vv.z, o2);
                o3 = fmaf(a, vv.w, o3);
            }
        }
        if (t < 7) {
            strip[(wv << 8) + (((t + 1) & 1) << 7) + (qh << 5) + kk] = sc[t + 1] * inv;
            float* vbn = kbuf + (((t + 1) & 1) << 12);
            ((float4*)vbn)[tid]       = v0;
            ((float4*)vbn)[tid + 512] = v1;
        }
        __syncthreads();
    }

    float4 oo; oo.x = o0; oo.y = o1; oo.z = o2; oo.w = o3;
    float* orow = out + ((size_t)(b * NQ) + q0 + (wv << 1) + qh) * NH;
    *(float4*)&orow[kk << 2] = oo;
}

extern "C" void kernel_launch(void* const* d_in, const int* in_sizes, int n_in,
                              void* d_out, int out_size, void* d_ws, size_t ws_size,
                              hipStream_t stream) {
    const float* q = (const float*)d_in[0];
    const float* k = (const float*)d_in[1];
    const float* v = (const float*)d_in[2];
    const float* w = (const float*)d_in[3];
    float* out = (float*)d_out;
    addattn_kernel<<<512, 512, 0, stream>>>(q, k, v, w, out);
}

// Round 6
// 216.394 us; speedup vs baseline: 5.7664x; 2.0698x over previous
//
#include <hip/hip_runtime.h>
#include <math.h>

#define C2 2.8853900817779268f   // 2*log2(e)

// prep: EkT[b][h][k] = exp2(C2 * K[b][k][h])   (k-major transpose, 4 MB in d_ws)
__global__ __launch_bounds__(512) void addattn_prep(const float* __restrict__ k_g,
                                                    float* __restrict__ ekt)
{
    int tid = blockIdx.x * 512 + threadIdx.x;   // 262144 threads
    int b   = tid >> 13;
    int r   = tid & 8191;
    int h4  = r >> 8;          // 0..31
    int k   = r & 255;         // 0..255
    float4 kv = *(const float4*)(k_g + ((size_t)(b * 256 + k)) * 128 + (h4 << 2));
    float* dst = ekt + (size_t)b * 32768 + (h4 << 10) + k;   // h-row stride 256 floats
    dst[0]   = __builtin_amdgcn_exp2f(C2 * kv.x);
    dst[256] = __builtin_amdgcn_exp2f(C2 * kv.y);
    dst[512] = __builtin_amdgcn_exp2f(C2 * kv.z);
    dst[768] = __builtin_amdgcn_exp2f(C2 * kv.w);
}

// main: barrier-free, no K/V LDS staging. 512 blocks x 512 thr; wave = 2 q rows.
__global__ __launch_bounds__(512, 8) void addattn_kernel(
    const float* __restrict__ q_g, const float* __restrict__ ekt,
    const float* __restrict__ v_g, const float* __restrict__ w_g,
    float* __restrict__ out)
{
    __shared__ float strip[4096];   // 16 KB: 512 floats per wave (Eq 0..255, then attn 0..511)

    const int tid  = threadIdx.x;
    const int lane = tid & 63;
    const int wv   = tid >> 6;     // 0..7
    const int kk   = lane & 31;
    const int qh   = lane >> 5;    // which of the wave's 2 q rows

    // XCD-grouped remap: each XCD's 64 blocks cover 4 whole batches (K/V L2 reuse)
    const int o    = ((blockIdx.x & 7) << 6) + (blockIdx.x >> 3);
    const int b    = o >> 4;
    const int q0   = (o & 15) << 4;
    const int qrow = q0 + (wv << 1) + qh;

    float* wstrip = strip + (wv << 9);    // wave-private 512 floats

    // ---- Eq = exp2(C2*q) -> wstrip[qh*128 + h]  (wave-private, no barrier) ----
    {
        const float* qp = q_g + ((size_t)(b * 256 + qrow)) * 128 + (kk << 2);
        float4 qv = *(const float4*)qp;
        float4 E;
        E.x = __builtin_amdgcn_exp2f(C2 * qv.x);
        E.y = __builtin_amdgcn_exp2f(C2 * qv.y);
        E.z = __builtin_amdgcn_exp2f(C2 * qv.z);
        E.w = __builtin_amdgcn_exp2f(C2 * qv.w);
        *(float4*)&wstrip[(qh << 7) + (kk << 2)] = E;
    }

    // ---- score: sc[t] over k = t*32+kk; EkT reads are coalesced + half-wave dup ----
    float sc[8] = {0.f, 0.f, 0.f, 0.f, 0.f, 0.f, 0.f, 0.f};
    const float* ek = ekt + (size_t)b * 32768 + kk;
    #pragma unroll 4
    for (int h4 = 0; h4 < 32; ++h4) {
        float4 e4 = *(const float4*)&wstrip[(qh << 7) + (h4 << 2)];  // 2-addr bcast
        float4 w4 = *(const float4*)(w_g + (h4 << 2));               // block-uniform, L1
        const float* ekh = ek + (h4 << 10);
        #pragma unroll
        for (int hi = 0; hi < 4; ++hi) {
            float eq = (&e4.x)[hi];
            float wi = (&w4.x)[hi];
            const float* ekr = ekh + (hi << 8);
            #pragma unroll
            for (int t = 0; t < 8; ++t) {                 // static offsets, 8 indep chains
                float den = fmaf(eq, ekr[t << 5], 1.0f);
                sc[t] = fmaf(wi, __builtin_amdgcn_rcpf(den), sc[t]);
            }
        }
    }

    // ---- softmax per half-wave (one q row each); score = -2*acc, log2e folded ----
    #pragma unroll
    for (int j = 0; j < 8; ++j) sc[j] *= -C2;
    float m = sc[0];
    #pragma unroll
    for (int j = 1; j < 8; ++j) m = fmaxf(m, sc[j]);
    #pragma unroll
    for (int off = 16; off; off >>= 1) m = fmaxf(m, __shfl_xor(m, off));
    float ssum = 0.f;
    #pragma unroll
    for (int j = 0; j < 8; ++j) { sc[j] = __builtin_amdgcn_exp2f(sc[j] - m); ssum += sc[j]; }
    #pragma unroll
    for (int off = 16; off; off >>= 1) ssum += __shfl_xor(ssum, off);
    const float inv = __builtin_amdgcn_rcpf(ssum);

    // attn -> wstrip[qh*256 + t*32 + kk]  (Eq region dead; wave program order = safe)
    #pragma unroll
    for (int j = 0; j < 8; ++j) wstrip[(qh << 8) + (j << 5) + kk] = sc[j] * inv;

    // ---- PV: V straight from global (L1/L2-hot, half-wave dup); lane owns h=4*kk.. ----
    float o0 = 0.f, o1 = 0.f, o2 = 0.f, o3 = 0.f;
    const float* vb = v_g + (size_t)b * 32768 + (kk << 2);
    const float* ap = wstrip + (qh << 8);
    #pragma unroll 4
    for (int k4 = 0; k4 < 64; ++k4) {
        float4 a4 = *(const float4*)(ap + (k4 << 2));     // 2-addr bcast
        #pragma unroll
        for (int i = 0; i < 4; ++i) {
            float4 vv = *(const float4*)(vb + ((size_t)((k4 << 2) + i) << 7));
            float a = (&a4.x)[i];
            o0 = fmaf(a, vv.x, o0);
            o1 = fmaf(a, vv.y, o1);
            o2 = fmaf(a, vv.z, o2);
            o3 = fmaf(a, vv.w, o3);
        }
    }

    float4 oo; oo.x = o0; oo.y = o1; oo.z = o2; oo.w = o3;
    *(float4*)(out + ((size_t)(b * 256) + qrow) * 128 + (kk << 2)) = oo;
}

extern "C" void kernel_launch(void* const* d_in, const int* in_sizes, int n_in,
                              void* d_out, int out_size, void* d_ws, size_t ws_size,
                              hipStream_t stream) {
    const float* q = (const float*)d_in[0];
    const float* k = (const float*)d_in[1];
    const float* v = (const float*)d_in[2];
    const float* w = (const float*)d_in[3];
    float* out = (float*)d_out;
    float* ekt = (float*)d_ws;                 // needs 32*128*256*4 = 4 MB
    addattn_prep<<<512, 512, 0, stream>>>(k, ekt);
    addattn_kernel<<<512, 512, 0, stream>>>(q, ekt, v, w, out);
}

// Round 7
// 130.019 us; speedup vs baseline: 9.5972x; 1.6643x over previous
//
#include <hip/hip_runtime.h>
#include <math.h>

#define C2 2.8853900817779268f   // 2*log2(e)

typedef __attribute__((address_space(3))) unsigned int       lds_u32;
typedef const __attribute__((address_space(1))) unsigned int g_u32;

__device__ __forceinline__ void stage16(const float* g, float* l) {
    // HW writes lane i at l + i*16B; l must be wave-uniform, g is per-lane
    __builtin_amdgcn_global_load_lds((g_u32*)g, (lds_u32*)l, 16, 0, 0);
}

// prep: EkT4[b][t][h4][k32][hi] = exp2(C2 * K[b][k=t*32+k32][h=4*h4+hi])
// tile = 4096 floats (16 KB), contiguous -> main kernel stages it linearly.
__global__ __launch_bounds__(512) void addattn_prep(const float* __restrict__ k_g,
                                                    float* __restrict__ ekt)
{
    int tid = blockIdx.x * 512 + threadIdx.x;   // 262144 threads
    int b   = tid >> 13;
    int r   = tid & 8191;
    int h4  = r >> 8;           // 0..31
    int k   = r & 255;          // 0..255
    float4 kv = *(const float4*)(k_g + ((size_t)(b * 256 + k)) * 128 + (h4 << 2));
    float4 E;
    E.x = __builtin_amdgcn_exp2f(C2 * kv.x);
    E.y = __builtin_amdgcn_exp2f(C2 * kv.y);
    E.z = __builtin_amdgcn_exp2f(C2 * kv.z);
    E.w = __builtin_amdgcn_exp2f(C2 * kv.w);
    *(float4*)(ekt + (size_t)b * 32768 + ((k >> 5) << 12) + (h4 << 7) + ((k & 31) << 2)) = E;
}

// main: 512 blocks x 512 thr (8 waves); wave = 2 q rows (one per half-wave).
// Score: 8 K-tiles (32 k-rows) async-staged, double-buffered. Scores -> LDS.
// PV: 8 V-tiles staged the same way.
__global__ __launch_bounds__(512, 4) void addattn_kernel(
    const float* __restrict__ q_g, const float* __restrict__ ekt,
    const float* __restrict__ v_g, const float* __restrict__ w_g,
    float* __restrict__ out)
{
    __shared__ float dbuf[8192];    // 32 KB: 2 x 16KB tile double-buffer (Ek, then V)
    __shared__ float strip[6144];   // 24 KB: per-wave 768 floats: Eq[256] | scores[512]; attn overlays [0..511]

    const int tid  = threadIdx.x;
    const int lane = tid & 63;
    const int wv   = tid >> 6;     // 0..7
    const int kk   = lane & 31;
    const int qh   = lane >> 5;    // which of the wave's 2 q rows

    // XCD-grouped remap: 4 whole batches per XCD -> K/V/Ek stay L2-hot
    const int o    = ((blockIdx.x & 7) << 6) + (blockIdx.x >> 3);
    const int b    = o >> 4;
    const int q0   = (o & 15) << 4;
    const int qrow = q0 + (wv << 1) + qh;

    float* wstrip = strip + wv * 768;
    const float* ek_base = ekt + (size_t)b * 32768;
    const float* v_base  = v_g + (size_t)b * 32768;

    // async-stage K tile 0 into dbuf[0] (2 x 1KB pieces per wave)
    {
        const float* g = ek_base + (wv << 8) + (lane << 2);
        float* l = dbuf + (wv << 8);
        stage16(g, l);
        stage16(g + 2048, l + 2048);
    }

    // Eq = exp2(C2*q) -> wstrip[qh*128 + h] (overlaps tile-0 staging latency)
    {
        const float* qp = q_g + (size_t)(b * 256 + qrow) * 128 + (kk << 2);
        float4 qv = *(const float4*)qp;
        float4 E;
        E.x = __builtin_amdgcn_exp2f(C2 * qv.x);
        E.y = __builtin_amdgcn_exp2f(C2 * qv.y);
        E.z = __builtin_amdgcn_exp2f(C2 * qv.z);
        E.w = __builtin_amdgcn_exp2f(C2 * qv.w);
        *(float4*)&wstrip[(qh << 7) + (kk << 2)] = E;
    }
    __syncthreads();   // drains tile-0 loads (vmcnt) + block barrier

    // ---- score phase ----
    const float* eqb  = wstrip + (qh << 7);
    float* sbase = wstrip + 256 + (qh << 8);
    #pragma unroll 1
    for (int t = 0; t < 8; ++t) {
        if (t < 7) {   // issue next K tile into the other buffer (async, no VGPRs)
            const float* g = ek_base + ((t + 1) << 12) + (wv << 8) + (lane << 2);
            float* l = dbuf + (((t + 1) & 1) << 12) + (wv << 8);
            stage16(g, l);
            stage16(g + 2048, l + 2048);
        }
        const float* kb = dbuf + ((t & 1) << 12) + (kk << 2);
        float s0 = 0.f, s1 = 0.f;
        #pragma unroll
        for (int h4 = 0; h4 < 32; h4 += 2) {
            float4 w4a = *(const float4*)(w_g + (h4 << 2));          // scalar (uniform)
            float4 e4a = *(const float4*)(eqb + (h4 << 2));          // LDS broadcast
            float4 k4a = *(const float4*)(kb + (h4 << 7));           // static imm offset
            float4 w4b = *(const float4*)(w_g + ((h4 + 1) << 2));
            float4 e4b = *(const float4*)(eqb + ((h4 + 1) << 2));
            float4 k4b = *(const float4*)(kb + ((h4 + 1) << 7));
            #pragma unroll
            for (int i = 0; i < 4; ++i) {
                float dA = fmaf((&e4a.x)[i], (&k4a.x)[i], 1.0f);
                float dB = fmaf((&e4b.x)[i], (&k4b.x)[i], 1.0f);
                s0 = fmaf((&w4a.x)[i], __builtin_amdgcn_rcpf(dA), s0);
                s1 = fmaf((&w4b.x)[i], __builtin_amdgcn_rcpf(dB), s1);
            }
        }
        sbase[(t << 5) + kk] = -C2 * (s0 + s1);   // pre-scaled score, wave-private
        __syncthreads();
    }

    // ---- stage V tile 0 (async) then softmax overlaps its latency ----
    {
        const float* g = v_base + (wv << 8) + (lane << 2);
        float* l = dbuf + (wv << 8);
        stage16(g, l);
        stage16(g + 2048, l + 2048);
    }
    // softmax per half-wave (row qh); lane kk holds k = 8kk..8kk+7
    const float* srd = wstrip + 256 + (qh << 8) + (kk << 3);
    float4 sa = *(const float4*)srd;
    float4 sb = *(const float4*)(srd + 4);
    float m = fmaxf(fmaxf(fmaxf(sa.x, sa.y), fmaxf(sa.z, sa.w)),
                    fmaxf(fmaxf(sb.x, sb.y), fmaxf(sb.z, sb.w)));
    #pragma unroll
    for (int off = 16; off; off >>= 1) m = fmaxf(m, __shfl_xor(m, off));
    float e0 = __builtin_amdgcn_exp2f(sa.x - m), e1 = __builtin_amdgcn_exp2f(sa.y - m);
    float e2 = __builtin_amdgcn_exp2f(sa.z - m), e3 = __builtin_amdgcn_exp2f(sa.w - m);
    float e4 = __builtin_amdgcn_exp2f(sb.x - m), e5 = __builtin_amdgcn_exp2f(sb.y - m);
    float e6 = __builtin_amdgcn_exp2f(sb.z - m), e7 = __builtin_amdgcn_exp2f(sb.w - m);
    float ssum = ((e0 + e1) + (e2 + e3)) + ((e4 + e5) + (e6 + e7));
    #pragma unroll
    for (int off = 16; off; off >>= 1) ssum += __shfl_xor(ssum, off);
    const float inv = __builtin_amdgcn_rcpf(ssum);
    float4 a0; a0.x = e0 * inv; a0.y = e1 * inv; a0.z = e2 * inv; a0.w = e3 * inv;
    float4 a1; a1.x = e4 * inv; a1.y = e5 * inv; a1.z = e6 * inv; a1.w = e7 * inv;
    // attn overlays wstrip[0..511] (Eq dead; same-wave ds ordering makes score reads safe)
    *(float4*)&wstrip[(qh << 8) + (kk << 3)]     = a0;
    *(float4*)&wstrip[(qh << 8) + (kk << 3) + 4] = a1;
    __syncthreads();   // V tile 0 landed

    // ---- PV phase: lane owns h = 4kk..4kk+3 of its row ----
    float o0 = 0.f, o1 = 0.f, o2 = 0.f, o3 = 0.f;
    const float* apb = wstrip + (qh << 8);
    #pragma unroll 1
    for (int t = 0; t < 8; ++t) {
        if (t < 7) {
            const float* g = v_base + ((t + 1) << 12) + (wv << 8) + (lane << 2);
            float* l = dbuf + (((t + 1) & 1) << 12) + (wv << 8);
            stage16(g, l);
            stage16(g + 2048, l + 2048);
        }
        const float* vb = dbuf + ((t & 1) << 12) + (kk << 2);
        const float* ap = apb + (t << 5);
        #pragma unroll
        for (int g8 = 0; g8 < 8; ++g8) {
            float4 a4 = *(const float4*)(ap + (g8 << 2));            // LDS broadcast
            #pragma unroll
            for (int i = 0; i < 4; ++i) {
                float4 vv = *(const float4*)(vb + (((g8 << 2) + i) << 7));  // static imm
                float a = (&a4.x)[i];
                o0 = fmaf(a, vv.x, o0);
                o1 = fmaf(a, vv.y, o1);
                o2 = fmaf(a, vv.z, o2);
                o3 = fmaf(a, vv.w, o3);
            }
        }
        if (t < 7) __syncthreads();
    }

    float4 oo; oo.x = o0; oo.y = o1; oo.z = o2; oo.w = o3;
    *(float4*)(out + ((size_t)(b * 256) + qrow) * 128 + (kk << 2)) = oo;
}

extern "C" void kernel_launch(void* const* d_in, const int* in_sizes, int n_in,
                              void* d_out, int out_size, void* d_ws, size_t ws_size,
                              hipStream_t stream) {
    const float* q = (const float*)d_in[0];
    const float* k = (const float*)d_in[1];
    const float* v = (const float*)d_in[2];
    const float* w = (const float*)d_in[3];
    float* out = (float*)d_out;
    float* ekt = (float*)d_ws;                 // 32*256*128*4 = 4 MB scratch
    addattn_prep<<<512, 512, 0, stream>>>(k, ekt);
    addattn_kernel<<<512, 512, 0, stream>>>(q, ekt, v, w, out);
}

// Round 8
// 54.955 us; speedup vs baseline: 22.7062x; 2.3659x over previous
//
#include <hip/hip_runtime.h>
#include <math.h>

#define C2 2.8853900817779268f   // 2*log2(e)

// prep: EkT[b][t8][hh2][g16][k32][hi4] = exp2(C2 * K[b][k=t*32+k32][h=hh*64+g*4+hi])
// One 32-k-row tile = 4096 floats (16 KB) contiguous -> main kernel stages linearly.
__global__ __launch_bounds__(512) void addattn_prep(const float* __restrict__ k_g,
                                                    float* __restrict__ ekt)
{
    int tid = blockIdx.x * 512 + threadIdx.x;   // 262144 threads
    int b   = tid >> 13;
    int r   = tid & 8191;
    int h4  = r >> 8;           // 0..31 (h-group of 4)
    int k   = r & 255;          // 0..255
    float4 kv = *(const float4*)(k_g + ((size_t)(b * 256 + k)) * 128 + (h4 << 2));
    float4 E;
    E.x = __builtin_amdgcn_exp2f(C2 * kv.x);
    E.y = __builtin_amdgcn_exp2f(C2 * kv.y);
    E.z = __builtin_amdgcn_exp2f(C2 * kv.z);
    E.w = __builtin_amdgcn_exp2f(C2 * kv.w);
    *(float4*)(ekt + (size_t)b * 32768 + ((k >> 5) << 12) + ((h4 >> 4) << 11)
               + ((h4 & 15) << 7) + ((k & 31) << 2)) = E;
}

// main: 512 blocks x 512 thr (8 waves). Wave = 2 q rows (sequential, register-blocked).
// Lane = (hh = h-half, kk = k-within-tile). Scores/attn in wave-private LDS.
__global__ __launch_bounds__(512, 4) void addattn_kernel(
    const float* __restrict__ q_g, const float* __restrict__ ekt,
    const float* __restrict__ v_g, const float* __restrict__ w_g,
    float* __restrict__ out)
{
    __shared__ float dbuf[8192];    // 32 KB: 2 x 16KB double-buffered 32-k-row tiles (Ek, then V)
    __shared__ float sattn[4096];   // 16 KB: per-wave [2 rows][256] scores -> attn (in place)
    __shared__ float eqw[2176];     // 8.5 KB: Eq (8 waves x 2 rows x 128) | w[128] at 2048

    const int tid  = threadIdx.x;
    const int lane = tid & 63;
    const int wv   = tid >> 6;     // 0..7
    const int kk   = lane & 31;    // k within tile
    const int hh   = lane >> 5;    // h-half (0: h<64, 1: h>=64)

    // XCD-grouped remap: 4 whole batches per XCD -> Ek/V/Q stay L2-hot
    const int o   = ((blockIdx.x & 7) << 6) + (blockIdx.x >> 3);
    const int b   = o >> 4;
    const int q0  = (o & 15) << 4;
    const int qr0 = q0 + (wv << 1);   // wave's first q row

    // w -> LDS once (512 B)
    if (tid < 32) ((float4*)&eqw[2048])[tid] = ((const float4*)w_g)[tid];

    // Eq = exp2(C2*q) for the wave's 2 rows: half-wave hh loads row hh
    {
        float4 qv = *(const float4*)(q_g + (size_t)(b * 256 + qr0 + hh) * 128 + (kk << 2));
        float4 E;
        E.x = __builtin_amdgcn_exp2f(C2 * qv.x);
        E.y = __builtin_amdgcn_exp2f(C2 * qv.y);
        E.z = __builtin_amdgcn_exp2f(C2 * qv.z);
        E.w = __builtin_amdgcn_exp2f(C2 * qv.w);
        *(float4*)&eqw[(wv << 8) + (hh << 7) + (kk << 2)] = E;
    }

    const float4* ek4 = (const float4*)(ekt + (size_t)b * 32768);
    const float4* vg4 = (const float4*)(v_g + (size_t)b * 32768);

    // stage Ek tile 0 (linear copy, coalesced, conflict-free)
    ((float4*)dbuf)[tid]       = ek4[tid];
    ((float4*)dbuf)[tid + 512] = ek4[tid + 512];
    __syncthreads();

    const float* eqb = eqw + (wv << 8) + (hh << 6);   // + r*128 + g*4
    const float* wb  = eqw + 2048 + (hh << 6);        // + g*4
    float* srow = sattn + (wv << 9);                  // [r*256 + k]

    // ---- score phase: 8 tiles of 32 k, double-buffered; partial over h-half ----
    #pragma unroll 1
    for (int t = 0; t < 8; ++t) {
        float4 p0, p1;
        if (t < 7) { p0 = ek4[((t + 1) << 10) + tid]; p1 = ek4[((t + 1) << 10) + 512 + tid]; }
        const float* kb = dbuf + ((t & 1) << 12) + (hh << 11) + (kk << 2);
        float s0 = 0.f, s1 = 0.f;
        #pragma unroll
        for (int g = 0; g < 16; ++g) {
            float4 k4 = *(const float4*)(kb + (g << 7));          // per-lane, conflict-free
            float4 w4 = *(const float4*)(wb + (g << 2));          // 2-addr broadcast
            float4 e0 = *(const float4*)(eqb + (g << 2));         // row 0 Eq
            float4 e1 = *(const float4*)(eqb + 128 + (g << 2));   // row 1 Eq
            #pragma unroll
            for (int i = 0; i < 4; ++i) {
                float kvv = (&k4.x)[i], wi = (&w4.x)[i];
                float d0 = fmaf((&e0.x)[i], kvv, 1.0f);
                float d1 = fmaf((&e1.x)[i], kvv, 1.0f);
                s0 = fmaf(wi, __builtin_amdgcn_rcpf(d0), s0);
                s1 = fmaf(wi, __builtin_amdgcn_rcpf(d1), s1);
            }
        }
        s0 += __shfl_xor(s0, 32);       // combine h-halves
        s1 += __shfl_xor(s1, 32);
        srow[(t << 5) + kk]       = -C2 * s0;   // both halves write same value (benign)
        srow[256 + (t << 5) + kk] = -C2 * s1;
        if (t < 7) {
            float* d = dbuf + (((t + 1) & 1) << 12);
            ((float4*)d)[tid] = p0; ((float4*)d)[tid + 512] = p1;
        }
        __syncthreads();
    }

    // ---- V tile 0 prefetch; softmax (per row, 64-lane) overlaps the latency ----
    float4 pv0 = vg4[tid], pv1 = vg4[tid + 512];

    #pragma unroll
    for (int r = 0; r < 2; ++r) {
        float4 sv = *(const float4*)&srow[(r << 8) + (lane << 2)];
        float mx = fmaxf(fmaxf(sv.x, sv.y), fmaxf(sv.z, sv.w));
        #pragma unroll
        for (int off = 32; off; off >>= 1) mx = fmaxf(mx, __shfl_xor(mx, off));
        float ex = __builtin_amdgcn_exp2f(sv.x - mx);
        float ey = __builtin_amdgcn_exp2f(sv.y - mx);
        float ez = __builtin_amdgcn_exp2f(sv.z - mx);
        float ew = __builtin_amdgcn_exp2f(sv.w - mx);
        float sum = (ex + ey) + (ez + ew);
        #pragma unroll
        for (int off = 32; off; off >>= 1) sum += __shfl_xor(sum, off);
        float inv = __builtin_amdgcn_rcpf(sum);
        float4 at; at.x = ex * inv; at.y = ey * inv; at.z = ez * inv; at.w = ew * inv;
        *(float4*)&srow[(r << 8) + (lane << 2)] = at;    // attn in place (own-wave order)
    }

    ((float4*)dbuf)[tid]       = pv0;    // V tile 0 -> buffer 0, linear [32][128]
    ((float4*)dbuf)[tid + 512] = pv1;
    __syncthreads();

    // ---- PV phase: lane covers h = kk*4..+3, k-half hh*16..+15; both rows in regs ----
    float4 a0; a0.x = a0.y = a0.z = a0.w = 0.f;
    float4 a1; a1.x = a1.y = a1.z = a1.w = 0.f;
    #pragma unroll 1
    for (int t = 0; t < 8; ++t) {
        float4 p0, p1;
        if (t < 7) { p0 = vg4[((t + 1) << 10) + tid]; p1 = vg4[((t + 1) << 10) + 512 + tid]; }
        const float* vb  = dbuf + ((t & 1) << 12) + (hh << 11) + (kk << 2);
        const float* ar0 = srow + (t << 5) + (hh << 4);
        #pragma unroll
        for (int g = 0; g < 4; ++g) {
            float4 at0 = *(const float4*)(ar0 + (g << 2));         // row 0 attn (bcast)
            float4 at1 = *(const float4*)(ar0 + 256 + (g << 2));   // row 1 attn
            #pragma unroll
            for (int i = 0; i < 4; ++i) {
                float4 vvv = *(const float4*)(vb + (((g << 2) + i) << 7));  // conflict-free
                float c0 = (&at0.x)[i], c1 = (&at1.x)[i];
                a0.x = fmaf(c0, vvv.x, a0.x); a0.y = fmaf(c0, vvv.y, a0.y);
                a0.z = fmaf(c0, vvv.z, a0.z); a0.w = fmaf(c0, vvv.w, a0.w);
                a1.x = fmaf(c1, vvv.x, a1.x); a1.y = fmaf(c1, vvv.y, a1.y);
                a1.z = fmaf(c1, vvv.z, a1.z); a1.w = fmaf(c1, vvv.w, a1.w);
            }
        }
        if (t < 7) {
            float* d = dbuf + (((t + 1) & 1) << 12);
            ((float4*)d)[tid] = p0; ((float4*)d)[tid + 512] = p1;
            __syncthreads();
        }
    }

    // combine k-halves
    a0.x += __shfl_xor(a0.x, 32); a0.y += __shfl_xor(a0.y, 32);
    a0.z += __shfl_xor(a0.z, 32); a0.w += __shfl_xor(a0.w, 32);
    a1.x += __shfl_xor(a1.x, 32); a1.y += __shfl_xor(a1.y, 32);
    a1.z += __shfl_xor(a1.z, 32); a1.w += __shfl_xor(a1.w, 32);

    if (hh == 0) {
        *(float4*)(out + (size_t)(b * 256 + qr0) * 128 + (kk << 2))     = a0;
        *(float4*)(out + (size_t)(b * 256 + qr0 + 1) * 128 + (kk << 2)) = a1;
    }
}

extern "C" void kernel_launch(void* const* d_in, const int* in_sizes, int n_in,
                              void* d_out, int out_size, void* d_ws, size_t ws_size,
                              hipStream_t stream) {
    const float* q = (const float*)d_in[0];
    const float* k = (const float*)d_in[1];
    const float* v = (const float*)d_in[2];
    const float* w = (const float*)d_in[3];
    float* out = (float*)d_out;
    float* ekt = (float*)d_ws;                 // 32*256*128*4 = 4 MB scratch
    addattn_prep<<<512, 512, 0, stream>>>(k, ekt);
    addattn_kernel<<<512, 512, 0, stream>>>(q, ekt, v, w, out);
}